// Round 1
// baseline (623.287 us; speedup 1.0000x reference)
//
#include <hip/hip_runtime.h>
#include <stdint.h>

// Problem constants
#define SEQ   2048
#define NHEAD 16
#define DHEAD 64
#define NROWS 4096      // BSZ*SEQ
#define MDIM  2048      // model dim
#define QKVN  6144
#define NINST 64        // BSZ * 2*NHEAD attention instances
#define EPSF  1e-5f
#define LAMBDA_INIT 0.7999593627581f
#define QSCALE 0.18033688011112042f   // dh^-0.5 * log2(e): flash softmax runs in exp2 domain

typedef unsigned short u16;
typedef __attribute__((ext_vector_type(8))) short bf16x8;   // 8 bf16 = 4 VGPRs (guide §3)
typedef __attribute__((ext_vector_type(4))) float f32x4;
typedef __attribute__((ext_vector_type(4))) unsigned short u16x4;

// async global->LDS, 16B/lane. LDS dest is wave-uniform base + lane*16 (guide §5 caveat),
// so LDS layout is forced contiguous in lane order; we XOR-swizzle the GLOBAL chunk index
// instead so ds_read_b128 fragment reads are 2-way-conflict-free (free per m136).
#define GLD_LDS16(g, l) \
  __builtin_amdgcn_global_load_lds((const __attribute__((address_space(1))) void*)(g), \
                                   (__attribute__((address_space(3))) void*)(l), 16, 0, 0)

__device__ __forceinline__ u16 f2bf(float f) {
  union { float f; uint32_t u; } v; v.f = f;
  return (u16)((v.u + 0x7fffu + ((v.u >> 16) & 1u)) >> 16);   // RNE
}
__device__ __forceinline__ float bf2f(uint32_t s) {
  union { uint32_t u; float f; } v; v.u = s << 16; return v.f;
}

// ---------------- cast fp32 -> bf16 (vectorized) ----------------
__global__ __launch_bounds__(256) void k_cast(const float4* __restrict__ src,
                                              u16* __restrict__ dst, int n4) {
  int i = blockIdx.x * 256 + threadIdx.x;
  if (i < n4) {
    float4 f = src[i];
    u16x4 o;
    o.x = f2bf(f.x); o.y = f2bf(f.y); o.z = f2bf(f.z); o.w = f2bf(f.w);
    *(u16x4*)(dst + (size_t)i * 4) = o;
  }
}

// ---------------- BT-GEMM: C(MxN) = A(MxK) @ B(NxK)^T, bf16 in, fp32/bf16 out ----
// m97 recipe: 128x128 tile, BK=64, 4 waves each 64x64, 16x16x32 bf16 MFMA,
// global_load_lds staging, XOR chunk swizzle.
template<int BF16OUT>
__global__ __launch_bounds__(256) void k_gemm_bt(const u16* __restrict__ A,
                                                 const u16* __restrict__ B,
                                                 void* __restrict__ Cp,
                                                 int M, int N, int K) {
  __shared__ __align__(16) u16 As[128 * 64];
  __shared__ __align__(16) u16 Bs[128 * 64];
  const int t = threadIdx.x, w = t >> 6, l = t & 63, n = l & 15, g = l >> 4;
  const int m0 = blockIdx.y * 128, n0 = blockIdx.x * 128;
  const int wm = (w >> 1) * 64, wn = (w & 1) * 64;
  f32x4 acc[4][4];
  #pragma unroll
  for (int i = 0; i < 4; i++)
    #pragma unroll
    for (int j = 0; j < 4; j++) acc[i][j] = (f32x4){0.f, 0.f, 0.f, 0.f};

  for (int kt = 0; kt < K; kt += 64) {
    #pragma unroll
    for (int p = 0; p < 4; ++p) {
      int id = p * 256 + t;
      int row = id >> 3, cc = id & 7, ccg = (cc ^ row) & 7;
      GLD_LDS16(A + (size_t)(m0 + row) * K + kt + ccg * 8, As + (size_t)(p * 256 + w * 64) * 8);
      GLD_LDS16(B + (size_t)(n0 + row) * K + kt + ccg * 8, Bs + (size_t)(p * 256 + w * 64) * 8);
    }
    __syncthreads();
    bf16x8 af[4][2], bfr[4][2];
    #pragma unroll
    for (int mi = 0; mi < 4; mi++) {
      int row = wm + mi * 16 + n;
      #pragma unroll
      for (int c = 0; c < 2; c++)
        af[mi][c] = *(const bf16x8*)(As + ((size_t)row * 8 + (((c * 4 + g) ^ row) & 7)) * 8);
    }
    #pragma unroll
    for (int ni = 0; ni < 4; ni++) {
      int row = wn + ni * 16 + n;
      #pragma unroll
      for (int c = 0; c < 2; c++)
        bfr[ni][c] = *(const bf16x8*)(Bs + ((size_t)row * 8 + (((c * 4 + g) ^ row) & 7)) * 8);
    }
    #pragma unroll
    for (int mi = 0; mi < 4; mi++)
      #pragma unroll
      for (int ni = 0; ni < 4; ni++)
        #pragma unroll
        for (int c = 0; c < 2; c++)
          acc[mi][ni] = __builtin_amdgcn_mfma_f32_16x16x32_bf16(af[mi][c], bfr[ni][c], acc[mi][ni], 0, 0, 0);
    __syncthreads();
  }
  // C/D layout (m89-verified): col = lane&15, row = (lane>>4)*4 + reg
  #pragma unroll
  for (int mi = 0; mi < 4; mi++)
    #pragma unroll
    for (int ni = 0; ni < 4; ni++)
      #pragma unroll
      for (int r = 0; r < 4; r++) {
        int row = m0 + wm + mi * 16 + g * 4 + r;
        int col = n0 + wn + ni * 16 + n;
        if (BF16OUT) ((u16*)Cp)[(size_t)row * N + col] = f2bf(acc[mi][ni][r]);
        else         ((float*)Cp)[(size_t)row * N + col] = acc[mi][ni][r];
      }
}

// ---------------- RoPE + repack Q,K into per-instance layout ----------------
// QKV row r (=b*SEQ+s): cols [0,2048) Q, [2048,4096) K. rope-head rh = col/64,
// pair (2i,2i+1) with angle [s][i]. inst = b*32 + rh. Q gets QSCALE folded in.
__global__ __launch_bounds__(256) void k_rope(const u16* __restrict__ QKV,
                                              const float* __restrict__ cosb,
                                              const float* __restrict__ sinb,
                                              u16* __restrict__ Qo, u16* __restrict__ Ko) {
  int tid = blockIdx.x * 256 + threadIdx.x;     // 2 * 4096 * 1024 = 2^23 threads
  int tensor = tid >> 22;
  int rem = tid & ((1 << 22) - 1);
  int r = rem >> 10;
  int p = rem & 1023;
  int rh = p >> 5, i = p & 31;
  int s = r & (SEQ - 1);
  int col = tensor * 2048 + rh * 64 + 2 * i;
  uint32_t u = *(const uint32_t*)(QKV + (size_t)r * QKVN + col);
  float a = bf2f(u & 0xffffu), bb = bf2f(u >> 16);
  float c = cosb[s * 32 + i], sn = sinb[s * 32 + i];
  float o0 = a * c - bb * sn;
  float o1 = a * sn + bb * c;
  if (tensor == 0) { o0 *= QSCALE; o1 *= QSCALE; }
  int inst = (r >> 11) * 32 + rh;
  u16* dst = (tensor ? Ko : Qo) + ((size_t)inst * SEQ + s) * 64 + 2 * i;
  *(uint32_t*)dst = (uint32_t)f2bf(o0) | ((uint32_t)f2bf(o1) << 16);
}

// ---------------- V transpose: QKV V-cols -> Vt[bh][128][SEQ] ----------------
__global__ __launch_bounds__(256) void k_vtrans(const u16* __restrict__ QKV,
                                                u16* __restrict__ Vt) {
  __shared__ __align__(16) u16 tile[64 * 80];   // pad to 160B stride: 2-way on loads
  int t = threadIdx.x;
  int st = blockIdx.x, dt = blockIdx.y, bh = blockIdx.z;
  int b = bh >> 4, h = bh & 15;
  #pragma unroll
  for (int p = 0; p < 2; p++) {
    int id = p * 256 + t, sr = id >> 3, cc = id & 7;
    const u16* gsrc = QKV + (size_t)(b * SEQ + st * 64 + sr) * QKVN + 4096 + h * 128 + dt * 64 + cc * 8;
    *(uint4*)(tile + sr * 80 + cc * 8) = *(const uint4*)gsrc;
  }
  __syncthreads();
  #pragma unroll
  for (int p = 0; p < 2; p++) {
    int id = p * 256 + t, dr = id >> 3, cc = id & 7;
    union { u16 v[8]; uint4 q; } uu;
    #pragma unroll
    for (int j = 0; j < 8; j++) uu.v[j] = tile[(cc * 8 + j) * 80 + dr];
    u16* gdst = Vt + ((size_t)bh * 128 + dt * 64 + dr) * SEQ + st * 64 + cc * 8;
    *(uint4*)gdst = uu.q;
  }
}

// ---------------- lambda scalar ----------------
__global__ __launch_bounds__(64) void k_lambda(const float* lq1, const float* lk1,
                                               const float* lq2, const float* lk2,
                                               float* out) {
  int l = threadIdx.x;
  float s1 = lq1[l] * lk1[l];
  float s2 = lq2[l] * lk2[l];
  #pragma unroll
  for (int d = 1; d < 64; d <<= 1) { s1 += __shfl_xor(s1, d); s2 += __shfl_xor(s2, d); }
  if (l == 0) *out = expf(s1) - expf(s2) + LAMBDA_INIT;
}

// ---------------- flash attention (causal), dqk=64, dv=128 ----------------
// grid (qtile=32, inst=64); block 256 = 4 waves; wave w owns q-rows [qb+16w, qb+16w+16).
// P C-layout -> A-layout via per-wave LDS round trip (m120-verified pattern).
__global__ __launch_bounds__(256) void k_flash(const u16* __restrict__ Q,
                                               const u16* __restrict__ K,
                                               const u16* __restrict__ V,
                                               u16* __restrict__ O) {
  __shared__ __align__(16) u16 Ks[64 * 64];
  __shared__ __align__(16) u16 Vs[128 * 64];
  __shared__ __align__(16) u16 Ps[4 * 1024];
  const int t = threadIdx.x, w = t >> 6, l = t & 63, n = l & 15, g = l >> 4;
  const int inst = blockIdx.y, qb = blockIdx.x * 64;
  const int b = inst >> 5, rh = inst & 31, h = rh >> 1, bh = b * 16 + h;
  const u16* Qp = Q + (size_t)inst * SEQ * 64;
  const u16* Kp = K + (size_t)inst * SEQ * 64;
  const u16* Vp = V + (size_t)bh * 128 * SEQ;
  u16* Pw = Ps + w * 1024;

  const int qrow_w = qb + w * 16;
  bf16x8 qf[2];
  #pragma unroll
  for (int c = 0; c < 2; c++)
    qf[c] = *(const bf16x8*)(Qp + (size_t)(qrow_w + n) * 64 + c * 32 + g * 8);

  f32x4 o_acc[8];
  #pragma unroll
  for (int nb = 0; nb < 8; nb++) o_acc[nb] = (f32x4){0.f, 0.f, 0.f, 0.f};
  float mrun[4], lrun[4];
  #pragma unroll
  for (int r = 0; r < 4; r++) { mrun[r] = -1e30f; lrun[r] = 0.f; }

  const int nkt = qb / 64 + 1;
  for (int kt = 0; kt < nkt; ++kt) {
    #pragma unroll
    for (int p = 0; p < 2; p++) {      // K tile: 64x64
      int id = p * 256 + t, row = id >> 3, cc = id & 7, ccg = (cc ^ row) & 7;
      GLD_LDS16(Kp + (size_t)(kt * 64 + row) * 64 + ccg * 8, Ks + (size_t)(p * 256 + w * 64) * 8);
    }
    #pragma unroll
    for (int p = 0; p < 4; p++) {      // V tile: 128(dv) x 64(keys), from Vt
      int id = p * 256 + t, row = id >> 3, cc = id & 7, ccg = (cc ^ row) & 7;
      GLD_LDS16(Vp + (size_t)row * SEQ + kt * 64 + ccg * 8, Vs + (size_t)(p * 256 + w * 64) * 8);
    }
    __syncthreads();

    // S = Q K^T (exp2-domain logits; QSCALE prefolded)
    f32x4 sa[4];
    #pragma unroll
    for (int kb = 0; kb < 4; kb++) {
      f32x4 z = (f32x4){0.f, 0.f, 0.f, 0.f};
      #pragma unroll
      for (int c = 0; c < 2; c++) {
        int krow = kb * 16 + n;
        bf16x8 kf = *(const bf16x8*)(Ks + ((size_t)krow * 8 + (((c * 4 + g) ^ krow) & 7)) * 8);
        z = __builtin_amdgcn_mfma_f32_16x16x32_bf16(qf[c], kf, z, 0, 0, 0);
      }
      sa[kb] = z;
    }
    // causal mask + online softmax (rows 4g+r, cols n per 16-block)
    float mt[4];
    #pragma unroll
    for (int r = 0; r < 4; r++) {
      int qrow = qrow_w + g * 4 + r;
      float mm = -1e30f;
      #pragma unroll
      for (int kb = 0; kb < 4; kb++) {
        int key = kt * 64 + kb * 16 + n;
        float s = sa[kb][r];
        if (key > qrow) s = -1e30f;
        sa[kb][r] = s;
        mm = fmaxf(mm, s);
      }
      mt[r] = mm;
    }
    #pragma unroll
    for (int d = 1; d < 16; d <<= 1)
      #pragma unroll
      for (int r = 0; r < 4; r++) mt[r] = fmaxf(mt[r], __shfl_xor(mt[r], d));
    float alpha[4], rs[4];
    #pragma unroll
    for (int r = 0; r < 4; r++) {
      float mn = fmaxf(mrun[r], mt[r]);
      alpha[r] = exp2f(mrun[r] - mn);
      mrun[r] = mn;
      rs[r] = 0.f;
    }
    #pragma unroll
    for (int kb = 0; kb < 4; kb++)
      #pragma unroll
      for (int r = 0; r < 4; r++) {
        float pv = exp2f(sa[kb][r] - mrun[r]);
        sa[kb][r] = pv;
        rs[r] += pv;
      }
    #pragma unroll
    for (int d = 1; d < 16; d <<= 1)
      #pragma unroll
      for (int r = 0; r < 4; r++) rs[r] += __shfl_xor(rs[r], d);
    #pragma unroll
    for (int r = 0; r < 4; r++) lrun[r] = lrun[r] * alpha[r] + rs[r];
    #pragma unroll
    for (int nb = 0; nb < 8; nb++)
      #pragma unroll
      for (int r = 0; r < 4; r++) o_acc[nb][r] *= alpha[r];

    // P: C-layout -> LDS (XOR-swizzled) -> A-layout
    #pragma unroll
    for (int kb = 0; kb < 4; kb++)
      #pragma unroll
      for (int r = 0; r < 4; r++) {
        int row = g * 4 + r, col = kb * 16 + n;
        Pw[row * 64 + ((((col >> 3) ^ row) & 7) * 8 + (col & 7))] = f2bf(sa[kb][r]);
      }
    // O += P @ V
    #pragma unroll
    for (int c = 0; c < 2; c++) {
      bf16x8 pf = *(const bf16x8*)(Pw + ((size_t)n * 8 + (((c * 4 + g) ^ n) & 7)) * 8);
      #pragma unroll
      for (int nb = 0; nb < 8; nb++) {
        int vrow = nb * 16 + n;
        bf16x8 vf = *(const bf16x8*)(Vs + ((size_t)vrow * 8 + (((c * 4 + g) ^ vrow) & 7)) * 8);
        o_acc[nb] = __builtin_amdgcn_mfma_f32_16x16x32_bf16(pf, vf, o_acc[nb], 0, 0, 0);
      }
    }
    __syncthreads();
  }
  float inv[4];
  #pragma unroll
  for (int r = 0; r < 4; r++) inv[r] = 1.0f / lrun[r];
  u16* Op = O + (size_t)inst * SEQ * 128;
  #pragma unroll
  for (int nb = 0; nb < 8; nb++)
    #pragma unroll
    for (int r = 0; r < 4; r++) {
      int qrow = qrow_w + g * 4 + r;
      Op[(size_t)qrow * 128 + nb * 16 + n] = f2bf(o_acc[nb][r] * inv[r]);
    }
}

// ---------------- combine: attn1 - lam*attn2, RMSNorm(128), subln, (1-li) -----
__global__ __launch_bounds__(256) void k_combine(const u16* __restrict__ Ob,
                                                 const float* __restrict__ subw,
                                                 const float* __restrict__ lamp,
                                                 u16* __restrict__ At) {
  const int t = threadIdx.x, w = t >> 6, l = t & 63;
  const int W = blockIdx.x * 4 + w;          // (b*SEQ+s)*16 + h
  const int hh = W & 15, row = W >> 4;
  const int b = row >> 11, s = row & (SEQ - 1);
  const float lam = *lamp;
  const size_t base = ((size_t)(b * 32 + hh * 2) * SEQ + s) * 128 + 2 * l;
  uint32_t u1 = *(const uint32_t*)(Ob + base);
  uint32_t u2 = *(const uint32_t*)(Ob + base + (size_t)SEQ * 128);
  float a0 = bf2f(u1 & 0xffffu) - lam * bf2f(u2 & 0xffffu);
  float a1 = bf2f(u1 >> 16)     - lam * bf2f(u2 >> 16);
  float ss = a0 * a0 + a1 * a1;
  #pragma unroll
  for (int d = 1; d < 64; d <<= 1) ss += __shfl_xor(ss, d);
  float rms = rsqrtf(ss * (1.0f / 128.0f) + EPSF);
  float k = rms * (1.0f - LAMBDA_INIT);
  u16 r0 = f2bf(a0 * subw[2 * l] * k);
  u16 r1 = f2bf(a1 * subw[2 * l + 1] * k);
  *(uint32_t*)(At + (size_t)row * MDIM + hh * 128 + 2 * l) = (uint32_t)r0 | ((uint32_t)r1 << 16);
}

// ---------------- host ----------------
extern "C" void kernel_launch(void* const* d_in, const int* in_sizes, int n_in,
                              void* d_out, int out_size, void* d_ws, size_t ws_size,
                              hipStream_t stream) {
  const float* x    = (const float*)d_in[0];
  const float* wq   = (const float*)d_in[1];
  const float* wk   = (const float*)d_in[2];
  const float* wv   = (const float*)d_in[3];
  const float* wo   = (const float*)d_in[4];
  const float* lq1  = (const float*)d_in[5];
  const float* lk1  = (const float*)d_in[6];
  const float* lq2  = (const float*)d_in[7];
  const float* lk2  = (const float*)d_in[8];
  const float* subw = (const float*)d_in[9];
  const float* rc   = (const float*)d_in[10];
  const float* rsn  = (const float*)d_in[11];

  char* ws = (char*)d_ws;
  u16*  Xbf  = (u16*)(ws + 0);            //  16.78 MB
  u16*  Wqkv = (u16*)(ws + 16777216);     //  25.17 MB (wq|wk|wv rows)
  u16*  Wob  = (u16*)(ws + 41943040);     //   8.39 MB
  u16*  QKV  = (u16*)(ws + 50331648);     //  50.33 MB
  u16*  Qb   = (u16*)(ws + 100663296);    //  16.78 MB
  u16*  Kb   = (u16*)(ws + 117440512);    //  16.78 MB
  u16*  Vt   = (u16*)(ws + 134217728);    //  16.78 MB
  u16*  Ob   = (u16*)(ws + 150994944);    //  33.55 MB
  u16*  At   = (u16*)(ws + 184549376);    //  16.78 MB
  float* lam = (float*)(ws + 201326592);
  if (ws_size < 201326600) return;        // workspace insufficient -> fail loudly via absmax

  k_cast<<<8192, 256, 0, stream>>>((const float4*)x,  Xbf, 2097152);
  k_cast<<<4096, 256, 0, stream>>>((const float4*)wq, Wqkv,            1048576);
  k_cast<<<4096, 256, 0, stream>>>((const float4*)wk, Wqkv + 4194304,  1048576);
  k_cast<<<4096, 256, 0, stream>>>((const float4*)wv, Wqkv + 8388608,  1048576);
  k_cast<<<4096, 256, 0, stream>>>((const float4*)wo, Wob, 1048576);

  k_gemm_bt<1><<<dim3(48, 32), 256, 0, stream>>>(Xbf, Wqkv, QKV, NROWS, QKVN, MDIM);
  k_rope<<<32768, 256, 0, stream>>>(QKV, rc, rsn, Qb, Kb);
  k_vtrans<<<dim3(32, 2, 32), 256, 0, stream>>>(QKV, Vt);
  k_lambda<<<1, 64, 0, stream>>>(lq1, lk1, lq2, lk2, lam);
  k_flash<<<dim3(32, 64), 256, 0, stream>>>(Qb, Kb, Vt, Ob);
  k_combine<<<16384, 256, 0, stream>>>(Ob, subw, lam, At);
  k_gemm_bt<0><<<dim3(16, 32), 256, 0, stream>>>(At, Wob, d_out, NROWS, MDIM, MDIM);
}